// Round 8
// baseline (504.698 us; speedup 1.0000x reference)
//
#include <hip/hip_runtime.h>
#include <hip/hip_bf16.h>
#include <math.h>

#define N_NODES 100000
#define N_EDGES 1600000
#define F_IN 256
#define H_DIM 128
#define N_GRAPHS 1000

#define NB_BUCKETS ((N_NODES + 255) >> 8)   // 391 buckets of 256 nodes
#define BSTRIDE 392
#define A_BLOCKS 256
#define EPB (N_EDGES / A_BLOCKS)            // 6250 edges per block (exact)

typedef unsigned short bfu;  // bf16 bit pattern
typedef short short8 __attribute__((ext_vector_type(8)));   // 8 bf16 = 4 VGPR
typedef float f32x4 __attribute__((ext_vector_type(4)));    // MFMA accum

__device__ __forceinline__ float b2f(unsigned u) {
    union { unsigned int i; float f; } v;
    v.i = u << 16;
    return v.f;
}
__device__ __forceinline__ bfu f2b(float f) {
    __hip_bfloat16 h = __float2bfloat16(f);  // RNE
    return *reinterpret_cast<bfu*>(&h);
}

// ---------------- CSR build: bucketed counting sort ----------------
__global__ __launch_bounds__(256) void k_hist(const int* __restrict__ dst,
                                              int* __restrict__ cnt_bb) {
    __shared__ int h[BSTRIDE];
    const int t = threadIdx.x;
    for (int i = t; i < BSTRIDE; i += 256) h[i] = 0;
    __syncthreads();
    const int base = blockIdx.x * EPB;
    for (int i = t; i < EPB; i += 256) atomicAdd(&h[dst[base + i] >> 8], 1);
    __syncthreads();
    for (int i = t; i < NB_BUCKETS; i += 256) cnt_bb[blockIdx.x * BSTRIDE + i] = h[i];
}

__global__ __launch_bounds__(256) void k_scan_blocks(int* __restrict__ cnt_bb,
                                                     int* __restrict__ btot) {
    __shared__ int s[256];
    const int t = threadIdx.x;
    const int b = blockIdx.x;
    int v = cnt_bb[t * BSTRIDE + b];
    s[t] = v;
    __syncthreads();
    for (int off = 1; off < 256; off <<= 1) {
        int u = (t >= off) ? s[t - off] : 0;
        __syncthreads();
        s[t] += u;
        __syncthreads();
    }
    cnt_bb[t * BSTRIDE + b] = s[t] - v;
    if (t == 255) btot[b] = s[255];
}

__global__ __launch_bounds__(512) void k_scan_buckets(const int* __restrict__ btot,
                                                      int* __restrict__ bucket_base) {
    __shared__ int s[512];
    const int t = threadIdx.x;
    int v = (t < NB_BUCKETS) ? btot[t] : 0;
    s[t] = v;
    __syncthreads();
    for (int off = 1; off < 512; off <<= 1) {
        int u = (t >= off) ? s[t - off] : 0;
        __syncthreads();
        s[t] += u;
        __syncthreads();
    }
    if (t < NB_BUCKETS) bucket_base[t] = s[t] - v;
    if (t == 0) bucket_base[NB_BUCKETS] = N_EDGES;
}

__global__ __launch_bounds__(256) void k_stage(const int* __restrict__ src,
                                               const int* __restrict__ dst,
                                               const int* __restrict__ cnt_bb,
                                               const int* __restrict__ bucket_base,
                                               unsigned* __restrict__ staging) {
    __shared__ int cur[BSTRIDE];
    const int t = threadIdx.x;
    const int blk = blockIdx.x;
    for (int i = t; i < NB_BUCKETS; i += 256)
        cur[i] = bucket_base[i] + cnt_bb[blk * BSTRIDE + i];
    __syncthreads();
    const int base = blk * EPB;
    for (int i = t; i < EPB; i += 256) {
        int d = dst[base + i];
        int s = src[base + i];
        int b = d >> 8;
        int pos = atomicAdd(&cur[b], 1);
        staging[pos] = (unsigned)s | ((unsigned)(d & 255) << 24);
    }
}

__global__ __launch_bounds__(256) void k_bucket(const unsigned* __restrict__ staging,
                                                const int* __restrict__ bucket_base,
                                                int* __restrict__ row_ptr,
                                                float* __restrict__ dis,
                                                int* __restrict__ col) {
    __shared__ int h[256];
    __shared__ int sc[256];
    __shared__ int cur[256];
    const int t = threadIdx.x;
    const int b = blockIdx.x;
    const int s0 = bucket_base[b];
    const int ne = bucket_base[b + 1] - s0;
    h[t] = 0;
    __syncthreads();
    for (int i = t; i < ne; i += 256) atomicAdd(&h[staging[s0 + i] >> 24], 1);
    __syncthreads();
    int myc = h[t];
    sc[t] = myc;
    __syncthreads();
    for (int off = 1; off < 256; off <<= 1) {
        int u = (t >= off) ? sc[t - off] : 0;
        __syncthreads();
        sc[t] += u;
        __syncthreads();
    }
    int excl = sc[t] - myc;
    int node = b * 256 + t;
    if (node <= N_NODES) row_ptr[node] = s0 + excl;
    if (node < N_NODES) dis[node] = rsqrtf((float)(myc + 1));
    cur[t] = s0 + excl;
    __syncthreads();
    for (int i = t; i < ne; i += 256) {
        unsigned u = staging[s0 + i];
        int pos = atomicAdd(&cur[u >> 24], 1);
        col[pos] = (int)(u & 0xFFFFFFu);
    }
}

// ---------------- W pre-pack: fp32 W[K][128] -> bf16 B-fragments ----------------
__global__ void k_wpack(const float* __restrict__ W, bfu* __restrict__ Wp, int K) {
    int u = blockIdx.x * 256 + threadIdx.x;
    int total = (K / 32) * 8 * 64;
    if (u >= total) return;
    int lane = u & 63;
    int nf = (u >> 6) & 7;
    int ks = u >> 9;
    int k = ks * 32 + (lane >> 4) * 8;
    int n = nf * 16 + (lane & 15);
    bfu o[8];
#pragma unroll
    for (int j = 0; j < 8; ++j) o[j] = f2b(W[(k + j) * 128 + n]);
    uint4 pk;
    pk.x = (unsigned)o[0] | ((unsigned)o[1] << 16);
    pk.y = (unsigned)o[2] | ((unsigned)o[3] << 16);
    pk.z = (unsigned)o[4] | ((unsigned)o[5] << 16);
    pk.w = (unsigned)o[6] | ((unsigned)o[7] << 16);
    *(uint4*)&Wp[u * 8] = pk;
}

// ---------------- MFMA GEMM v2: 64-row tile, dbuf LDS + register prefetch ----------------
template <int K, typename AT>
__global__ __launch_bounds__(256) void k_mm_mfma(const AT* __restrict__ A,
                                                 const bfu* __restrict__ Wp,
                                                 const float* __restrict__ dis,
                                                 bfu* __restrict__ C, int M) {
    __shared__ bfu As[2][64 * 40];   // 64 rows x 32 bf16, pitch 80 B, double-buffered
    const int t = threadIdx.x;
    const int w = t >> 6;
    const int l = t & 63;
    const int l15 = l & 15;
    const int lhi = l >> 4;
    const int row0 = blockIdx.x * 64;
    constexpr int KS = K / 32;

    f32x4 acc[8];
#pragma unroll
    for (int nf = 0; nf < 8; ++nf) acc[nf] = (f32x4)0.0f;

    float4 pf0 = make_float4(0.f, 0.f, 0.f, 0.f), pf1 = pf0;
    uint4 pb = make_uint4(0u, 0u, 0u, 0u);

    if constexpr (sizeof(AT) == 4) {
        int r0 = t >> 3, s0 = t & 7;
        int r1 = (t + 256) >> 3;
        if (row0 + r0 < M) pf0 = *(const float4*)&A[(long)(row0 + r0) * K + s0 * 4];
        if (row0 + r1 < M) pf1 = *(const float4*)&A[(long)(row0 + r1) * K + s0 * 4];
    } else {
        int r = t >> 2, s = t & 3;
        if (row0 + r < M) pb = *(const uint4*)&A[(long)(row0 + r) * K + s * 8];
    }

    int buf = 0;
    for (int ks = 0; ks < KS; ++ks) {
        if constexpr (sizeof(AT) == 4) {
            int r0 = t >> 3, s0 = t & 7;
            int r1 = (t + 256) >> 3;
            uint2 pk0, pk1;
            pk0.x = (unsigned)f2b(pf0.x) | ((unsigned)f2b(pf0.y) << 16);
            pk0.y = (unsigned)f2b(pf0.z) | ((unsigned)f2b(pf0.w) << 16);
            pk1.x = (unsigned)f2b(pf1.x) | ((unsigned)f2b(pf1.y) << 16);
            pk1.y = (unsigned)f2b(pf1.z) | ((unsigned)f2b(pf1.w) << 16);
            *(uint2*)&As[buf][r0 * 40 + s0 * 4] = pk0;
            *(uint2*)&As[buf][r1 * 40 + s0 * 4] = pk1;
        } else {
            *(uint4*)&As[buf][(t >> 2) * 40 + (t & 3) * 8] = pb;
        }
        if (ks + 1 < KS) {
            const int k0n = (ks + 1) * 32;
            if constexpr (sizeof(AT) == 4) {
                int r0 = t >> 3, s0 = t & 7;
                int r1 = (t + 256) >> 3;
                pf0 = make_float4(0.f, 0.f, 0.f, 0.f);
                pf1 = pf0;
                if (row0 + r0 < M) pf0 = *(const float4*)&A[(long)(row0 + r0) * K + k0n + s0 * 4];
                if (row0 + r1 < M) pf1 = *(const float4*)&A[(long)(row0 + r1) * K + k0n + s0 * 4];
            } else {
                int r = t >> 2, s = t & 3;
                pb = make_uint4(0u, 0u, 0u, 0u);
                if (row0 + r < M) pb = *(const uint4*)&A[(long)(row0 + r) * K + k0n + s * 8];
            }
        }
        __syncthreads();
        short8 af = *(const short8*)&As[buf][(w * 16 + l15) * 40 + lhi * 8];
        const bfu* wp = Wp + ((long)(ks * 8) * 64 + l) * 8;
#pragma unroll
        for (int nf = 0; nf < 8; ++nf) {
            short8 wf = *(const short8*)(wp + (long)nf * 64 * 8);
            acc[nf] = __builtin_amdgcn_mfma_f32_16x16x32_bf16(wf, af, acc[nf], 0, 0, 0);
        }
        buf ^= 1;
    }
    int row = row0 + w * 16 + l15;
    if (row < M) {
        float sc = dis[row];
        int nb0 = lhi * 4;
#pragma unroll
        for (int nf = 0; nf < 8; ++nf) {
            uint2 pk;
            pk.x = (unsigned)f2b(acc[nf][0] * sc) | ((unsigned)f2b(acc[nf][1] * sc) << 16);
            pk.y = (unsigned)f2b(acc[nf][2] * sc) | ((unsigned)f2b(acc[nf][3] * sc) << 16);
            *(uint2*)&C[(long)row * 128 + nf * 16 + nb0] = pk;
        }
    }
}

// ---------------- CSR gather aggregation v3: channel-split for XCD L2 affinity ----------------
// blockIdx = nb*2 + g; g selects the 128B half-row (channels g*64..g*64+63).
// Round-robin block->XCD dispatch => even XCDs only touch half 0, odd XCDs half 1:
// per-XCD compulsory t' traffic halves. 32 nodes/block, 8 lanes/node, 16B/lane.
__global__ __launch_bounds__(256) void k_agg(const int* __restrict__ row_ptr,
                                             const int* __restrict__ col,
                                             const float* __restrict__ dis,
                                             const bfu* __restrict__ tbuf,
                                             const float* __restrict__ b,
                                             bfu* __restrict__ h) {
    const int t = threadIdx.x;
    const int g = blockIdx.x & 1;
    const int nb = blockIdx.x >> 1;
    const int node = nb * 32 + (t >> 3);
    const int lane = t & 7;
    if (node >= N_NODES) return;
    const int ch = g * 64 + lane * 8;  // 8 channels (16 B)

    uint4 sv = *(const uint4*)&tbuf[(long)node * 128 + ch];
    float a0 = b2f(sv.x & 0xffff), a1 = b2f(sv.x >> 16);
    float a2 = b2f(sv.y & 0xffff), a3 = b2f(sv.y >> 16);
    float a4 = b2f(sv.z & 0xffff), a5 = b2f(sv.z >> 16);
    float a6 = b2f(sv.w & 0xffff), a7 = b2f(sv.w >> 16);

    int e = row_ptr[node];
    const int end = row_ptr[node + 1];
    for (; e + 7 < end; e += 8) {
        int s[8];
#pragma unroll
        for (int j = 0; j < 8; ++j) s[j] = col[e + j];
        uint4 v[8];
#pragma unroll
        for (int j = 0; j < 8; ++j) v[j] = *(const uint4*)&tbuf[(long)s[j] * 128 + ch];
#pragma unroll
        for (int j = 0; j < 8; ++j) {
            a0 += b2f(v[j].x & 0xffff); a1 += b2f(v[j].x >> 16);
            a2 += b2f(v[j].y & 0xffff); a3 += b2f(v[j].y >> 16);
            a4 += b2f(v[j].z & 0xffff); a5 += b2f(v[j].z >> 16);
            a6 += b2f(v[j].w & 0xffff); a7 += b2f(v[j].w >> 16);
        }
    }
    for (; e < end; ++e) {
        uint4 v = *(const uint4*)&tbuf[(long)col[e] * 128 + ch];
        a0 += b2f(v.x & 0xffff); a1 += b2f(v.x >> 16);
        a2 += b2f(v.y & 0xffff); a3 += b2f(v.y >> 16);
        a4 += b2f(v.z & 0xffff); a5 += b2f(v.z >> 16);
        a6 += b2f(v.w & 0xffff); a7 += b2f(v.w >> 16);
    }
    const float dn = dis[node];
    float4 bb0 = *(const float4*)&b[ch];
    float4 bb1 = *(const float4*)&b[ch + 4];
    float o0 = fmaxf(a0 * dn + bb0.x, 0.0f);
    float o1 = fmaxf(a1 * dn + bb0.y, 0.0f);
    float o2 = fmaxf(a2 * dn + bb0.z, 0.0f);
    float o3 = fmaxf(a3 * dn + bb0.w, 0.0f);
    float o4 = fmaxf(a4 * dn + bb1.x, 0.0f);
    float o5 = fmaxf(a5 * dn + bb1.y, 0.0f);
    float o6 = fmaxf(a6 * dn + bb1.z, 0.0f);
    float o7 = fmaxf(a7 * dn + bb1.w, 0.0f);
    uint4 pk;
    pk.x = (unsigned)f2b(o0) | ((unsigned)f2b(o1) << 16);
    pk.y = (unsigned)f2b(o2) | ((unsigned)f2b(o3) << 16);
    pk.z = (unsigned)f2b(o4) | ((unsigned)f2b(o5) << 16);
    pk.w = (unsigned)f2b(o6) | ((unsigned)f2b(o7) << 16);
    *(uint4*)&h[(long)node * 128 + ch] = pk;
}

// ---------------- graph segment bounds (batch is sorted) ----------------
__global__ void k_bounds(const int* __restrict__ batch, int* __restrict__ bounds) {
    int g = blockIdx.x * blockDim.x + threadIdx.x;
    if (g > N_GRAPHS) return;
    int lo = 0, hi = N_NODES;
    while (lo < hi) {
        int mid = (lo + hi) >> 1;
        if (batch[mid] < g) lo = mid + 1; else hi = mid;
    }
    bounds[g] = lo;
}

// ---------------- fused pool (mean over segment; h already relu'd) + MLP head ----------------
__global__ __launch_bounds__(128) void k_pool_head(const int* __restrict__ bounds,
                                                   const bfu* __restrict__ h,
                                                   const float* __restrict__ fw1, const float* __restrict__ fb1,
                                                   const float* __restrict__ fw2, const float* __restrict__ fb2,
                                                   float* __restrict__ out) {
    const int g = blockIdx.x;
    const int t = threadIdx.x;
    const int s = bounds[g], e = bounds[g + 1];
    float sum = 0.0f;
    int n = s;
    for (; n + 1 < e; n += 2) {
        sum += b2f(h[(long)n * 128 + t]);
        sum += b2f(h[(long)(n + 1) * 128 + t]);
    }
    if (n < e) sum += b2f(h[(long)n * 128 + t]);

    __shared__ float sg[128];
    __shared__ float sh[32];
    float inv = 1.0f / fmaxf((float)(e - s), 1.0f);
    sg[t] = sum * inv;
    __syncthreads();
    if (t < 32) {
        float a = fb1[t];
#pragma unroll 8
        for (int k = 0; k < 128; ++k) a += sg[k] * fw1[k * 32 + t];
        sh[t] = fmaxf(a, 0.0f);
    }
    __syncthreads();
    if (t == 0) {
        float l0 = fb2[0], l1 = fb2[1];
        for (int k = 0; k < 32; ++k) {
            l0 += sh[k] * fw2[k * 2];
            l1 += sh[k] * fw2[k * 2 + 1];
        }
        float m = fmaxf(l0, l1);
        float lse = m + logf(expf(l0 - m) + expf(l1 - m));
        out[g * 2 + 0] = l0 - lse;
        out[g * 2 + 1] = l1 - lse;
    }
}

extern "C" void kernel_launch(void* const* d_in, const int* in_sizes, int n_in,
                              void* d_out, int out_size, void* d_ws, size_t ws_size,
                              hipStream_t stream) {
    const float* x  = (const float*)d_in[0];
    const int* ei   = (const int*)d_in[1];
    const int* batch = (const int*)d_in[2];
    const float* W1 = (const float*)d_in[3];
    const float* b1 = (const float*)d_in[4];
    const float* W2 = (const float*)d_in[5];
    const float* b2 = (const float*)d_in[6];
    const float* W3 = (const float*)d_in[7];
    const float* b3 = (const float*)d_in[8];
    const float* fw1 = (const float*)d_in[9];
    const float* fb1 = (const float*)d_in[10];
    const float* fw2 = (const float*)d_in[11];
    const float* fb2 = (const float*)d_in[12];
    float* out = (float*)d_out;

    const int* src = ei;
    const int* dst = ei + N_EDGES;

    // workspace layout (all chunks multiple of 16 B)
    char* ws = (char*)d_ws;
    int*      cnt_bb      = (int*)ws;                            // 256*392
    int*      btot        = cnt_bb + A_BLOCKS * BSTRIDE;         // 392
    int*      bucket_base = btot + BSTRIDE;                      // 392+8
    unsigned* staging     = (unsigned*)(bucket_base + BSTRIDE + 8);  // E
    int*      row_ptr     = (int*)(staging + N_EDGES);           // N+4
    float*    dis         = (float*)(row_ptr + N_NODES + 4);     // N
    int*      col         = (int*)(dis + N_NODES);               // E
    int*      bounds      = col + N_EDGES;                       // G+1 (+pad)
    bfu*      wpack       = (bfu*)(bounds + N_GRAPHS + 8);       // 32768 bfu
    bfu*      buf0        = wpack + 32768;                       // N*128 bf16 (t')
    bfu*      buf1        = buf0 + (long)N_NODES * 128;          // N*128 bf16 (h)

    // ---- CSR build (counting sort) + norms + segment bounds ----
    k_hist<<<A_BLOCKS, 256, 0, stream>>>(dst, cnt_bb);
    k_scan_blocks<<<NB_BUCKETS, 256, 0, stream>>>(cnt_bb, btot);
    k_scan_buckets<<<1, 512, 0, stream>>>(btot, bucket_base);
    k_stage<<<A_BLOCKS, 256, 0, stream>>>(src, dst, cnt_bb, bucket_base, staging);
    k_bucket<<<NB_BUCKETS, 256, 0, stream>>>(staging, bucket_base, row_ptr, dis, col);
    k_bounds<<<(N_GRAPHS + 1 + 255) / 256, 256, 0, stream>>>(batch, bounds);

    const int mmGrid = (N_NODES + 63) / 64;        // 1563
    const int aggGrid = ((N_NODES + 31) / 32) * 2; // 6250 (nb*2+g)

    // layer 1 (A = x fp32, K=256)
    k_wpack<<<16, 256, 0, stream>>>(W1, wpack, F_IN);
    k_mm_mfma<F_IN, float><<<mmGrid, 256, 0, stream>>>(x, wpack, dis, buf0, N_NODES);
    k_agg<<<aggGrid, 256, 0, stream>>>(row_ptr, col, dis, buf0, b1, buf1);
    // layer 2 (A = h bf16, K=128)
    k_wpack<<<8, 256, 0, stream>>>(W2, wpack, H_DIM);
    k_mm_mfma<H_DIM, bfu><<<mmGrid, 256, 0, stream>>>(buf1, wpack, dis, buf0, N_NODES);
    k_agg<<<aggGrid, 256, 0, stream>>>(row_ptr, col, dis, buf0, b2, buf1);
    // layer 3
    k_wpack<<<8, 256, 0, stream>>>(W3, wpack, H_DIM);
    k_mm_mfma<H_DIM, bfu><<<mmGrid, 256, 0, stream>>>(buf1, wpack, dis, buf0, N_NODES);
    k_agg<<<aggGrid, 256, 0, stream>>>(row_ptr, col, dis, buf0, b3, buf1);

    // fused pool + head
    k_pool_head<<<N_GRAPHS, 128, 0, stream>>>(bounds, buf1, fw1, fb1, fw2, fb2, out);
}

// Round 9
// 401.352 us; speedup vs baseline: 1.2575x; 1.2575x over previous
//
#include <hip/hip_runtime.h>
#include <hip/hip_bf16.h>
#include <math.h>

#define N_NODES 100000
#define N_EDGES 1600000
#define F_IN 256
#define H_DIM 128
#define N_GRAPHS 1000

#define NB_BUCKETS ((N_NODES + 255) >> 8)   // 391 buckets of 256 nodes
#define BSTRIDE 392
#define A_BLOCKS 256
#define EPB (N_EDGES / A_BLOCKS)            // 6250 edges per block (exact)

typedef unsigned short bfu;  // bf16 bit pattern
typedef short short8 __attribute__((ext_vector_type(8)));   // 8 bf16 = 4 VGPR
typedef float f32x4 __attribute__((ext_vector_type(4)));    // MFMA accum

__device__ __forceinline__ float b2f(unsigned u) {
    union { unsigned int i; float f; } v;
    v.i = u << 16;
    return v.f;
}
__device__ __forceinline__ bfu f2b(float f) {
    __hip_bfloat16 h = __float2bfloat16(f);  // RNE
    return *reinterpret_cast<bfu*>(&h);
}

// ---------------- CSR build: bucketed counting sort ----------------
__global__ __launch_bounds__(256) void k_hist(const int* __restrict__ dst,
                                              int* __restrict__ cnt_bb) {
    __shared__ int h[BSTRIDE];
    const int t = threadIdx.x;
    for (int i = t; i < BSTRIDE; i += 256) h[i] = 0;
    __syncthreads();
    const int base = blockIdx.x * EPB;
    for (int i = t; i < EPB; i += 256) atomicAdd(&h[dst[base + i] >> 8], 1);
    __syncthreads();
    for (int i = t; i < NB_BUCKETS; i += 256) cnt_bb[blockIdx.x * BSTRIDE + i] = h[i];
}

__global__ __launch_bounds__(256) void k_scan_blocks(int* __restrict__ cnt_bb,
                                                     int* __restrict__ btot) {
    __shared__ int s[256];
    const int t = threadIdx.x;
    const int b = blockIdx.x;
    int v = cnt_bb[t * BSTRIDE + b];
    s[t] = v;
    __syncthreads();
    for (int off = 1; off < 256; off <<= 1) {
        int u = (t >= off) ? s[t - off] : 0;
        __syncthreads();
        s[t] += u;
        __syncthreads();
    }
    cnt_bb[t * BSTRIDE + b] = s[t] - v;
    if (t == 255) btot[b] = s[255];
}

__global__ __launch_bounds__(512) void k_scan_buckets(const int* __restrict__ btot,
                                                      int* __restrict__ bucket_base) {
    __shared__ int s[512];
    const int t = threadIdx.x;
    int v = (t < NB_BUCKETS) ? btot[t] : 0;
    s[t] = v;
    __syncthreads();
    for (int off = 1; off < 512; off <<= 1) {
        int u = (t >= off) ? s[t - off] : 0;
        __syncthreads();
        s[t] += u;
        __syncthreads();
    }
    if (t < NB_BUCKETS) bucket_base[t] = s[t] - v;
    if (t == 0) bucket_base[NB_BUCKETS] = N_EDGES;
}

__global__ __launch_bounds__(256) void k_stage(const int* __restrict__ src,
                                               const int* __restrict__ dst,
                                               const int* __restrict__ cnt_bb,
                                               const int* __restrict__ bucket_base,
                                               unsigned* __restrict__ staging) {
    __shared__ int cur[BSTRIDE];
    const int t = threadIdx.x;
    const int blk = blockIdx.x;
    for (int i = t; i < NB_BUCKETS; i += 256)
        cur[i] = bucket_base[i] + cnt_bb[blk * BSTRIDE + i];
    __syncthreads();
    const int base = blk * EPB;
    for (int i = t; i < EPB; i += 256) {
        int d = dst[base + i];
        int s = src[base + i];
        int b = d >> 8;
        int pos = atomicAdd(&cur[b], 1);
        staging[pos] = (unsigned)s | ((unsigned)(d & 255) << 24);
    }
}

__global__ __launch_bounds__(256) void k_bucket(const unsigned* __restrict__ staging,
                                                const int* __restrict__ bucket_base,
                                                int* __restrict__ row_ptr,
                                                float* __restrict__ dis,
                                                int* __restrict__ col) {
    __shared__ int h[256];
    __shared__ int sc[256];
    __shared__ int cur[256];
    const int t = threadIdx.x;
    const int b = blockIdx.x;
    const int s0 = bucket_base[b];
    const int ne = bucket_base[b + 1] - s0;
    h[t] = 0;
    __syncthreads();
    for (int i = t; i < ne; i += 256) atomicAdd(&h[staging[s0 + i] >> 24], 1);
    __syncthreads();
    int myc = h[t];
    sc[t] = myc;
    __syncthreads();
    for (int off = 1; off < 256; off <<= 1) {
        int u = (t >= off) ? sc[t - off] : 0;
        __syncthreads();
        sc[t] += u;
        __syncthreads();
    }
    int excl = sc[t] - myc;
    int node = b * 256 + t;
    if (node <= N_NODES) row_ptr[node] = s0 + excl;
    if (node < N_NODES) dis[node] = rsqrtf((float)(myc + 1));
    cur[t] = s0 + excl;
    __syncthreads();
    for (int i = t; i < ne; i += 256) {
        unsigned u = staging[s0 + i];
        int pos = atomicAdd(&cur[u >> 24], 1);
        col[pos] = (int)(u & 0xFFFFFFu);
    }
}

// ---------------- W pre-pack: fp32 W[K][128] -> bf16 B-fragments ----------------
__global__ void k_wpack(const float* __restrict__ W, bfu* __restrict__ Wp, int K) {
    int u = blockIdx.x * 256 + threadIdx.x;
    int total = (K / 32) * 8 * 64;
    if (u >= total) return;
    int lane = u & 63;
    int nf = (u >> 6) & 7;
    int ks = u >> 9;
    int k = ks * 32 + (lane >> 4) * 8;
    int n = nf * 16 + (lane & 15);
    bfu o[8];
#pragma unroll
    for (int j = 0; j < 8; ++j) o[j] = f2b(W[(k + j) * 128 + n]);
    uint4 pk;
    pk.x = (unsigned)o[0] | ((unsigned)o[1] << 16);
    pk.y = (unsigned)o[2] | ((unsigned)o[3] << 16);
    pk.z = (unsigned)o[4] | ((unsigned)o[5] << 16);
    pk.w = (unsigned)o[6] | ((unsigned)o[7] << 16);
    *(uint4*)&Wp[u * 8] = pk;
}

// ---------------- MFMA GEMM v2 (layer 1): 64-row tile, dbuf LDS + register prefetch ----------------
template <int K, typename AT>
__global__ __launch_bounds__(256) void k_mm_mfma(const AT* __restrict__ A,
                                                 const bfu* __restrict__ Wp,
                                                 const float* __restrict__ dis,
                                                 bfu* __restrict__ C, int M) {
    __shared__ bfu As[2][64 * 40];
    const int t = threadIdx.x;
    const int w = t >> 6;
    const int l = t & 63;
    const int l15 = l & 15;
    const int lhi = l >> 4;
    const int row0 = blockIdx.x * 64;
    constexpr int KS = K / 32;

    f32x4 acc[8];
#pragma unroll
    for (int nf = 0; nf < 8; ++nf) acc[nf] = (f32x4)0.0f;

    float4 pf0 = make_float4(0.f, 0.f, 0.f, 0.f), pf1 = pf0;
    uint4 pb = make_uint4(0u, 0u, 0u, 0u);

    if constexpr (sizeof(AT) == 4) {
        int r0 = t >> 3, s0 = t & 7;
        int r1 = (t + 256) >> 3;
        if (row0 + r0 < M) pf0 = *(const float4*)&A[(long)(row0 + r0) * K + s0 * 4];
        if (row0 + r1 < M) pf1 = *(const float4*)&A[(long)(row0 + r1) * K + s0 * 4];
    } else {
        int r = t >> 2, s = t & 3;
        if (row0 + r < M) pb = *(const uint4*)&A[(long)(row0 + r) * K + s * 8];
    }

    int buf = 0;
    for (int ks = 0; ks < KS; ++ks) {
        if constexpr (sizeof(AT) == 4) {
            int r0 = t >> 3, s0 = t & 7;
            int r1 = (t + 256) >> 3;
            uint2 pk0, pk1;
            pk0.x = (unsigned)f2b(pf0.x) | ((unsigned)f2b(pf0.y) << 16);
            pk0.y = (unsigned)f2b(pf0.z) | ((unsigned)f2b(pf0.w) << 16);
            pk1.x = (unsigned)f2b(pf1.x) | ((unsigned)f2b(pf1.y) << 16);
            pk1.y = (unsigned)f2b(pf1.z) | ((unsigned)f2b(pf1.w) << 16);
            *(uint2*)&As[buf][r0 * 40 + s0 * 4] = pk0;
            *(uint2*)&As[buf][r1 * 40 + s0 * 4] = pk1;
        } else {
            *(uint4*)&As[buf][(t >> 2) * 40 + (t & 3) * 8] = pb;
        }
        if (ks + 1 < KS) {
            const int k0n = (ks + 1) * 32;
            if constexpr (sizeof(AT) == 4) {
                int r0 = t >> 3, s0 = t & 7;
                int r1 = (t + 256) >> 3;
                pf0 = make_float4(0.f, 0.f, 0.f, 0.f);
                pf1 = pf0;
                if (row0 + r0 < M) pf0 = *(const float4*)&A[(long)(row0 + r0) * K + k0n + s0 * 4];
                if (row0 + r1 < M) pf1 = *(const float4*)&A[(long)(row0 + r1) * K + k0n + s0 * 4];
            } else {
                int r = t >> 2, s = t & 3;
                pb = make_uint4(0u, 0u, 0u, 0u);
                if (row0 + r < M) pb = *(const uint4*)&A[(long)(row0 + r) * K + k0n + s * 8];
            }
        }
        __syncthreads();
        short8 af = *(const short8*)&As[buf][(w * 16 + l15) * 40 + lhi * 8];
        const bfu* wp = Wp + ((long)(ks * 8) * 64 + l) * 8;
#pragma unroll
        for (int nf = 0; nf < 8; ++nf) {
            short8 wf = *(const short8*)(wp + (long)nf * 64 * 8);
            acc[nf] = __builtin_amdgcn_mfma_f32_16x16x32_bf16(wf, af, acc[nf], 0, 0, 0);
        }
        buf ^= 1;
    }
    int row = row0 + w * 16 + l15;
    if (row < M) {
        float sc = dis[row];
        int nb0 = lhi * 4;
#pragma unroll
        for (int nf = 0; nf < 8; ++nf) {
            uint2 pk;
            pk.x = (unsigned)f2b(acc[nf][0] * sc) | ((unsigned)f2b(acc[nf][1] * sc) << 16);
            pk.y = (unsigned)f2b(acc[nf][2] * sc) | ((unsigned)f2b(acc[nf][3] * sc) << 16);
            *(uint2*)&C[(long)row * 128 + nf * 16 + nb0] = pk;
        }
    }
}

// ---------------- gather helpers ----------------
__device__ __forceinline__ void acc8v(float* a, uint4 v) {
    a[0] += b2f(v.x & 0xffff); a[1] += b2f(v.x >> 16);
    a[2] += b2f(v.y & 0xffff); a[3] += b2f(v.y >> 16);
    a[4] += b2f(v.z & 0xffff); a[5] += b2f(v.z >> 16);
    a[6] += b2f(v.w & 0xffff); a[7] += b2f(v.w >> 16);
}
__device__ __forceinline__ void acc_row(float* a, const bfu* r) {
    uint4 v0 = *(const uint4*)(r);
    uint4 v1 = *(const uint4*)(r + 8);
    uint4 v2 = *(const uint4*)(r + 16);
    uint4 v3 = *(const uint4*)(r + 24);
    acc8v(a, v0); acc8v(a + 8, v1); acc8v(a + 16, v2); acc8v(a + 24, v3);
}

// ---------------- FUSED agg+mm: t_next = ( relu(dis*(gather t_prev)+b) @ W ) * dis ----------------
// 256 threads; 64 dst nodes/block; gather: 4 lanes/node, 32 ch/lane; then 4-wave MFMA from LDS.
// Numerics identical to separate agg(bf16 store)+mm(bf16 LDS) path.
template <int KNEXT>
__global__ __launch_bounds__(256) void k_agg_mm(const int* __restrict__ row_ptr,
                                                const int* __restrict__ col,
                                                const float* __restrict__ dis,
                                                const bfu* __restrict__ tprev,
                                                const float* __restrict__ bvec,
                                                const bfu* __restrict__ Wp,
                                                bfu* __restrict__ tnext, int M) {
    __shared__ bfu Hs[64 * 136];  // 64 rows x 128 bf16, pitch 136 (272 B)
    const int t = threadIdx.x;
    const int nrow = t >> 2;                 // 0..63
    const int node = blockIdx.x * 64 + nrow;
    const int lz = t & 3;
    const int ch = lz * 32;                  // this lane's 32 channels

    if (node < M) {
        float a[32];
#pragma unroll
        for (int j = 0; j < 32; ++j) a[j] = 0.0f;
        const bfu* tp = tprev + ch;
        acc_row(a, tp + (long)node * 128);   // self term
        int e = row_ptr[node];
        const int end = row_ptr[node + 1];
        for (; e + 1 < end; e += 2) {
            int s0 = col[e], s1 = col[e + 1];
            acc_row(a, tp + (long)s0 * 128);
            acc_row(a, tp + (long)s1 * 128);
        }
        if (e < end) acc_row(a, tp + (long)col[e] * 128);
        const float dn = dis[node];
        uint pk[16];
#pragma unroll
        for (int j = 0; j < 16; ++j) {
            float lo = fmaxf(a[2 * j] * dn + bvec[ch + 2 * j], 0.0f);
            float hi = fmaxf(a[2 * j + 1] * dn + bvec[ch + 2 * j + 1], 0.0f);
            pk[j] = (unsigned)f2b(lo) | ((unsigned)f2b(hi) << 16);
        }
        bfu* hrow = &Hs[nrow * 136 + ch];
#pragma unroll
        for (int q = 0; q < 4; ++q)
            *(uint4*)(hrow + q * 8) = make_uint4(pk[4 * q], pk[4 * q + 1], pk[4 * q + 2], pk[4 * q + 3]);
    }
    __syncthreads();
    // ---- MFMA from LDS: 4 waves x 16 rows ----
    const int w = t >> 6, l = t & 63, l15 = l & 15, lhi = l >> 4;
    f32x4 acc[8];
#pragma unroll
    for (int nf = 0; nf < 8; ++nf) acc[nf] = (f32x4)0.0f;
    constexpr int KS = KNEXT / 32;
#pragma unroll
    for (int ks = 0; ks < KS; ++ks) {
        short8 af = *(const short8*)&Hs[(w * 16 + l15) * 136 + ks * 32 + lhi * 8];
        const bfu* wp = Wp + ((long)(ks * 8) * 64 + l) * 8;
#pragma unroll
        for (int nf = 0; nf < 8; ++nf) {
            short8 wf = *(const short8*)(wp + (long)nf * 64 * 8);
            acc[nf] = __builtin_amdgcn_mfma_f32_16x16x32_bf16(wf, af, acc[nf], 0, 0, 0);
        }
    }
    int row = blockIdx.x * 64 + w * 16 + l15;
    if (row < M) {
        float sc = dis[row];
        int nb0 = lhi * 4;
#pragma unroll
        for (int nf = 0; nf < 8; ++nf) {
            uint2 pko;
            pko.x = (unsigned)f2b(acc[nf][0] * sc) | ((unsigned)f2b(acc[nf][1] * sc) << 16);
            pko.y = (unsigned)f2b(acc[nf][2] * sc) | ((unsigned)f2b(acc[nf][3] * sc) << 16);
            *(uint2*)&tnext[(long)row * 128 + nf * 16 + nb0] = pko;
        }
    }
}

// ---------------- standalone CSR gather agg (layer 3; R6-proven form) ----------------
__global__ __launch_bounds__(256) void k_agg(const int* __restrict__ row_ptr,
                                             const int* __restrict__ col,
                                             const float* __restrict__ dis,
                                             const bfu* __restrict__ tbuf,
                                             const float* __restrict__ b,
                                             bfu* __restrict__ h) {
    const int t = threadIdx.x;
    const int node = blockIdx.x * 8 + (t >> 5);
    const int lane = t & 31;
    if (node >= N_NODES) return;
    const int q = lane << 2;

    uint2 sv = *(const uint2*)&tbuf[(long)node * 128 + q];
    float a0 = b2f(sv.x & 0xffff);
    float a1 = b2f(sv.x >> 16);
    float a2 = b2f(sv.y & 0xffff);
    float a3 = b2f(sv.y >> 16);

    int e = row_ptr[node];
    const int end = row_ptr[node + 1];
    for (; e + 3 < end; e += 4) {
        int s0 = col[e], s1 = col[e + 1], s2 = col[e + 2], s3 = col[e + 3];
        uint2 v0 = *(const uint2*)&tbuf[(long)s0 * 128 + q];
        uint2 v1 = *(const uint2*)&tbuf[(long)s1 * 128 + q];
        uint2 v2 = *(const uint2*)&tbuf[(long)s2 * 128 + q];
        uint2 v3 = *(const uint2*)&tbuf[(long)s3 * 128 + q];
        a0 += (b2f(v0.x & 0xffff) + b2f(v1.x & 0xffff)) +
              (b2f(v2.x & 0xffff) + b2f(v3.x & 0xffff));
        a1 += (b2f(v0.x >> 16) + b2f(v1.x >> 16)) +
              (b2f(v2.x >> 16) + b2f(v3.x >> 16));
        a2 += (b2f(v0.y & 0xffff) + b2f(v1.y & 0xffff)) +
              (b2f(v2.y & 0xffff) + b2f(v3.y & 0xffff));
        a3 += (b2f(v0.y >> 16) + b2f(v1.y >> 16)) +
              (b2f(v2.y >> 16) + b2f(v3.y >> 16));
    }
    for (; e < end; ++e) {
        int s0 = col[e];
        uint2 v0 = *(const uint2*)&tbuf[(long)s0 * 128 + q];
        a0 += b2f(v0.x & 0xffff);
        a1 += b2f(v0.x >> 16);
        a2 += b2f(v0.y & 0xffff);
        a3 += b2f(v0.y >> 16);
    }
    const float dn = dis[node];
    float4 bb = *(const float4*)&b[q];
    float o0 = fmaxf(a0 * dn + bb.x, 0.0f);
    float o1 = fmaxf(a1 * dn + bb.y, 0.0f);
    float o2 = fmaxf(a2 * dn + bb.z, 0.0f);
    float o3 = fmaxf(a3 * dn + bb.w, 0.0f);
    uint2 pk;
    pk.x = (unsigned)f2b(o0) | ((unsigned)f2b(o1) << 16);
    pk.y = (unsigned)f2b(o2) | ((unsigned)f2b(o3) << 16);
    *(uint2*)&h[(long)node * 128 + q] = pk;
}

// ---------------- graph segment bounds (batch is sorted) ----------------
__global__ void k_bounds(const int* __restrict__ batch, int* __restrict__ bounds) {
    int g = blockIdx.x * blockDim.x + threadIdx.x;
    if (g > N_GRAPHS) return;
    int lo = 0, hi = N_NODES;
    while (lo < hi) {
        int mid = (lo + hi) >> 1;
        if (batch[mid] < g) lo = mid + 1; else hi = mid;
    }
    bounds[g] = lo;
}

// ---------------- fused pool (mean over segment; h already relu'd) + MLP head ----------------
__global__ __launch_bounds__(128) void k_pool_head(const int* __restrict__ bounds,
                                                   const bfu* __restrict__ h,
                                                   const float* __restrict__ fw1, const float* __restrict__ fb1,
                                                   const float* __restrict__ fw2, const float* __restrict__ fb2,
                                                   float* __restrict__ out) {
    const int g = blockIdx.x;
    const int t = threadIdx.x;
    const int s = bounds[g], e = bounds[g + 1];
    float sum = 0.0f;
    int n = s;
    for (; n + 1 < e; n += 2) {
        sum += b2f(h[(long)n * 128 + t]);
        sum += b2f(h[(long)(n + 1) * 128 + t]);
    }
    if (n < e) sum += b2f(h[(long)n * 128 + t]);

    __shared__ float sg[128];
    __shared__ float sh[32];
    float inv = 1.0f / fmaxf((float)(e - s), 1.0f);
    sg[t] = sum * inv;
    __syncthreads();
    if (t < 32) {
        float a = fb1[t];
#pragma unroll 8
        for (int k = 0; k < 128; ++k) a += sg[k] * fw1[k * 32 + t];
        sh[t] = fmaxf(a, 0.0f);
    }
    __syncthreads();
    if (t == 0) {
        float l0 = fb2[0], l1 = fb2[1];
        for (int k = 0; k < 32; ++k) {
            l0 += sh[k] * fw2[k * 2];
            l1 += sh[k] * fw2[k * 2 + 1];
        }
        float m = fmaxf(l0, l1);
        float lse = m + logf(expf(l0 - m) + expf(l1 - m));
        out[g * 2 + 0] = l0 - lse;
        out[g * 2 + 1] = l1 - lse;
    }
}

extern "C" void kernel_launch(void* const* d_in, const int* in_sizes, int n_in,
                              void* d_out, int out_size, void* d_ws, size_t ws_size,
                              hipStream_t stream) {
    const float* x  = (const float*)d_in[0];
    const int* ei   = (const int*)d_in[1];
    const int* batch = (const int*)d_in[2];
    const float* W1 = (const float*)d_in[3];
    const float* b1 = (const float*)d_in[4];
    const float* W2 = (const float*)d_in[5];
    const float* b2 = (const float*)d_in[6];
    const float* W3 = (const float*)d_in[7];
    const float* b3 = (const float*)d_in[8];
    const float* fw1 = (const float*)d_in[9];
    const float* fb1 = (const float*)d_in[10];
    const float* fw2 = (const float*)d_in[11];
    const float* fb2 = (const float*)d_in[12];
    float* out = (float*)d_out;

    const int* src = ei;
    const int* dst = ei + N_EDGES;

    // workspace layout (all chunks multiple of 16 B)
    char* ws = (char*)d_ws;
    int*      cnt_bb      = (int*)ws;                            // 256*392
    int*      btot        = cnt_bb + A_BLOCKS * BSTRIDE;         // 392
    int*      bucket_base = btot + BSTRIDE;                      // 392+8
    unsigned* staging     = (unsigned*)(bucket_base + BSTRIDE + 8);  // E
    int*      row_ptr     = (int*)(staging + N_EDGES);           // N+4
    float*    dis         = (float*)(row_ptr + N_NODES + 4);     // N
    int*      col         = (int*)(dis + N_NODES);               // E
    int*      bounds      = col + N_EDGES;                       // G+1 (+pad)
    bfu*      wpack1      = (bfu*)(bounds + N_GRAPHS + 8);       // 32768 bfu (K=256)
    bfu*      wpack2      = wpack1 + 32768;                      // 16384 bfu (K=128)
    bfu*      wpack3      = wpack2 + 16384;                      // 16384 bfu
    bfu*      buf0        = wpack3 + 16384;                      // N*128 bf16
    bfu*      buf1        = buf0 + (long)N_NODES * 128;          // N*128 bf16

    // ---- CSR build (counting sort) + norms + segment bounds + weight packs ----
    k_hist<<<A_BLOCKS, 256, 0, stream>>>(dst, cnt_bb);
    k_scan_blocks<<<NB_BUCKETS, 256, 0, stream>>>(cnt_bb, btot);
    k_scan_buckets<<<1, 512, 0, stream>>>(btot, bucket_base);
    k_stage<<<A_BLOCKS, 256, 0, stream>>>(src, dst, cnt_bb, bucket_base, staging);
    k_bucket<<<NB_BUCKETS, 256, 0, stream>>>(staging, bucket_base, row_ptr, dis, col);
    k_bounds<<<(N_GRAPHS + 1 + 255) / 256, 256, 0, stream>>>(batch, bounds);
    k_wpack<<<16, 256, 0, stream>>>(W1, wpack1, F_IN);
    k_wpack<<<8, 256, 0, stream>>>(W2, wpack2, H_DIM);
    k_wpack<<<8, 256, 0, stream>>>(W3, wpack3, H_DIM);

    const int mmGrid = (N_NODES + 63) / 64;       // 1563
    const int fusedGrid = (N_NODES + 63) / 64;    // 1563
    const int aggGrid = (N_NODES + 7) / 8;        // 12500

    // layer 1: t1 = (x @ W1) * dis
    k_mm_mfma<F_IN, float><<<mmGrid, 256, 0, stream>>>(x, wpack1, dis, buf0, N_NODES);
    // fused layer1-agg + layer2-mm: t2 = (relu(dis*gather(t1)+b1) @ W2) * dis
    k_agg_mm<H_DIM><<<fusedGrid, 256, 0, stream>>>(row_ptr, col, dis, buf0, b1, wpack2, buf1, N_NODES);
    // fused layer2-agg + layer3-mm: t3 = (relu(dis*gather(t2)+b2) @ W3) * dis
    k_agg_mm<H_DIM><<<fusedGrid, 256, 0, stream>>>(row_ptr, col, dis, buf1, b2, wpack3, buf0, N_NODES);
    // layer3 agg: h3 = relu(dis*gather(t3)+b3)
    k_agg<<<aggGrid, 256, 0, stream>>>(row_ptr, col, dis, buf0, b3, buf1);

    // fused pool + head
    k_pool_head<<<N_GRAPHS, 128, 0, stream>>>(bounds, buf1, fw1, fb1, fw2, fb2, out);
}